// Round 10
// baseline (9378.117 us; speedup 1.0000x reference)
//
#include <hip/hip_runtime.h>
#include <hip/hip_bf16.h>

#define NB 64
#define TT 1024
#define ND 512
#define NH 1024
#define GRID 256
#define NTH 64
#define HSLOT_Q ((size_t)NB * NH / 4)   // h slot size in 64-bit qwords (32K qwords = 128KB)
#define SENTD 0xFFFFFFFFu

typedef float f32x4 __attribute__((ext_vector_type(4)));
typedef unsigned u32x4 __attribute__((ext_vector_type(4)));
typedef __bf16 bf16x8 __attribute__((ext_vector_type(8)));
typedef unsigned long long u64;

__device__ __forceinline__ float sigmoid_f(float v) { return 1.0f / (1.0f + __expf(-v)); }

__device__ __forceinline__ float tanh_f(float v) {
    float a = fabsf(v);
    float e = __expf(-2.0f * a);
    float t = (1.0f - e) / (1.0f + e);
    return copysignf(t, v);
}

// Device-coherent accessors: relaxed AGENT atomics compile to sc1 global ops
// that the COMPILER tracks (exact waitcnt, spill-safe) — no inline asm.
__device__ __forceinline__ u64 ld_q(const u64* p) {
    return __hip_atomic_load(p, __ATOMIC_RELAXED, __HIP_MEMORY_SCOPE_AGENT);
}
__device__ __forceinline__ unsigned ld_d(const unsigned* p) {
    return __hip_atomic_load(p, __ATOMIC_RELAXED, __HIP_MEMORY_SCOPE_AGENT);
}
__device__ __forceinline__ void st_d(unsigned* p, unsigned v) {
    __hip_atomic_store(p, v, __ATOMIC_RELAXED, __HIP_MEMORY_SCOPE_AGENT);
}

// SINGLE-WAVE blocks: 64 threads own a full 16(batch)x16(hidden) tile with
// full K=1536. No __syncthreads in the step loop, no psum LDS exchange: the
// MFMA accumulators (r,z,nx,nh share D-layout) feed gate math directly.
// Sync substrate: 3 rotating sentinel-validated h slots (dword-atomic
// publish == validation; SENT=0xFFFFFFFF is unreachable as a bf16 pair).
__global__ void __launch_bounds__(NTH, 1) gru_kernel(
    const float* __restrict__ x, const float* __restrict__ W_ih,
    const float* __restrict__ W_hh, const float* __restrict__ b_ih,
    const float* __restrict__ b_hh, float* __restrict__ out,
    u64* __restrict__ hbase)
{
    extern __shared__ char smem[];
    __bf16* WihF = (__bf16*)smem;            // 16 ksteps * 3 gates * 512 = 49152 B
    __bf16* WhhF = WihF + 48 * 512;          // 32 ksteps * 3 gates * 512 = 98304 B

    const int tid = threadIdx.x;             // == lane
    const int bg = blockIdx.x >> 6;
    const int cg = blockIdx.x & 63;
    const int brow = bg << 4;
    const int hc0 = cg << 4;

    // ---- one-time: fragment-ordered weight LDS (fp32 -> bf16) ----
    for (int s = tid; s < 48 * 64; s += NTH) {           // W_ih slots (it*3+g)
        int ln = s & 63, r = s >> 6;
        int g = r % 3, it = r / 3;
        int k = it * 32 + (ln >> 4) * 8;
        int col = ln & 15;
        const float* src = W_ih + (size_t)(g * NH + hc0 + col) * ND + k;
        float4 va = *(const float4*)(src);
        float4 vb = *(const float4*)(src + 4);
        bf16x8 f;
        f[0] = (__bf16)va.x; f[1] = (__bf16)va.y; f[2] = (__bf16)va.z; f[3] = (__bf16)va.w;
        f[4] = (__bf16)vb.x; f[5] = (__bf16)vb.y; f[6] = (__bf16)vb.z; f[7] = (__bf16)vb.w;
        *(bf16x8*)(WihF + (size_t)s * 8) = f;
    }
    for (int s = tid; s < 96 * 64; s += NTH) {           // W_hh slots (it*3+g)
        int ln = s & 63, r = s >> 6;
        int g = r % 3, it = r / 3;
        int k = it * 32 + (ln >> 4) * 8;
        int col = ln & 15;
        const float* src = W_hh + (size_t)(g * NH + hc0 + col) * NH + k;
        float4 va = *(const float4*)(src);
        float4 vb = *(const float4*)(src + 4);
        bf16x8 f;
        f[0] = (__bf16)va.x; f[1] = (__bf16)va.y; f[2] = (__bf16)va.z; f[3] = (__bf16)va.w;
        f[4] = (__bf16)vb.x; f[5] = (__bf16)vb.y; f[6] = (__bf16)vb.z; f[7] = (__bf16)vb.w;
        *(bf16x8*)(WhhF + (size_t)s * 8) = f;
    }

    const int lane = tid;
    const int lcol = lane & 15;   // A-frag row (batch) / D col (hidden)
    const int kgrp = lane >> 4;

    const float b_r = b_ih[hc0 + lcol] + b_hh[hc0 + lcol];
    const float b_z = b_ih[NH + hc0 + lcol] + b_hh[NH + hc0 + lcol];
    const float b_nx = b_ih[2 * NH + hc0 + lcol];
    const float b_nh = b_hh[2 * NH + hc0 + lcol];

    __syncthreads();

    // consumer qword base: row = brow+lcol, k-slice starts at kgrp*8
    const size_t qbase = ((size_t)(brow + lcol) * NH + kgrp * 8) >> 2;
    // canary dword: producer block cg'=lane, row brow+15, element pair 14/15
    const size_t cndw = ((size_t)(brow + 15) * NH + lane * 16 + 14) >> 1;

    float hp[4] = {0.f, 0.f, 0.f, 0.f};

    // prologue: load + convert x(0)
    bf16x8 xf[16];
    {
        const float* xr = x + ((size_t)(brow + lcol) * TT + 0) * ND + kgrp * 8;
        #pragma unroll
        for (int it = 0; it < 16; ++it) {
            f32x4 a = *(const f32x4*)(xr + it * 32);
            f32x4 b = *(const f32x4*)(xr + it * 32 + 4);
            bf16x8 f;
            f[0] = (__bf16)a[0]; f[1] = (__bf16)a[1]; f[2] = (__bf16)a[2]; f[3] = (__bf16)a[3];
            f[4] = (__bf16)b[0]; f[5] = (__bf16)b[1]; f[6] = (__bf16)b[2]; f[7] = (__bf16)b[3];
            xf[it] = f;
        }
    }

    for (int t = 0; t < TT; ++t) {
        // ---- A. x-part: 48 MFMAs (register-only; peer stores land meanwhile) ----
        f32x4 ar{}, az{}, anx{}, anh{};
        #pragma unroll
        for (int it = 0; it < 16; ++it) {
            const __bf16* wp = WihF + (size_t)(it * 3) * 512 + lane * 8;
            bf16x8 wr = *(const bf16x8*)(wp);
            bf16x8 wz = *(const bf16x8*)(wp + 512);
            bf16x8 wn = *(const bf16x8*)(wp + 1024);
            ar  = __builtin_amdgcn_mfma_f32_16x16x32_bf16(xf[it], wr, ar, 0, 0, 0);
            az  = __builtin_amdgcn_mfma_f32_16x16x32_bf16(xf[it], wz, az, 0, 0, 0);
            anx = __builtin_amdgcn_mfma_f32_16x16x32_bf16(xf[it], wn, anx, 0, 0, 0);
        }

        // ---- B. bulk h(t) load: 64 tracked qword loads (compiler waits) ----
        const u64* hq_p = hbase + (size_t)(t % 3) * HSLOT_Q + qbase;
        u64 hq[64];
        #pragma unroll
        for (int i = 0; i < 32; ++i) {
            hq[2 * i]     = ld_q(hq_p + (size_t)i * 8);
            hq[2 * i + 1] = ld_q(hq_p + (size_t)i * 8 + 1);
        }

        // ---- C. validate every dword half; canary-spin + full reload on miss ----
        const unsigned* cn = (const unsigned*)(hbase + (size_t)(t % 3) * HSLOT_Q) + cndw;
        for (;;) {
            unsigned bad = 0;
            #pragma unroll
            for (int i = 0; i < 64; ++i) {
                bad |= ((unsigned)hq[i] == SENTD) | ((unsigned)(hq[i] >> 32) == SENTD);
            }
            if (__all(bad == 0)) break;
            for (;;) {
                unsigned c = ld_d(cn);
                if (__all(c != SENTD)) break;
                __builtin_amdgcn_s_sleep(1);
            }
            #pragma unroll
            for (int i = 0; i < 32; ++i) {
                hq[2 * i]     = ld_q(hq_p + (size_t)i * 8);
                hq[2 * i + 1] = ld_q(hq_p + (size_t)i * 8 + 1);
            }
        }

        // ---- D. h-part: 96 MFMAs; fragments assembled from qword pairs ----
        #pragma unroll
        for (int it = 0; it < 32; ++it) {
            u64 qa = hq[2 * it], qb = hq[2 * it + 1];
            u32x4 d;
            d[0] = (unsigned)qa; d[1] = (unsigned)(qa >> 32);
            d[2] = (unsigned)qb; d[3] = (unsigned)(qb >> 32);
            bf16x8 af = __builtin_bit_cast(bf16x8, d);
            const __bf16* wp = WhhF + (size_t)(it * 3) * 512 + lane * 8;
            bf16x8 wr = *(const bf16x8*)(wp);
            bf16x8 wz = *(const bf16x8*)(wp + 512);
            bf16x8 wn = *(const bf16x8*)(wp + 1024);
            ar  = __builtin_amdgcn_mfma_f32_16x16x32_bf16(af, wr, ar, 0, 0, 0);
            az  = __builtin_amdgcn_mfma_f32_16x16x32_bf16(af, wz, az, 0, 0, 0);
            anh = __builtin_amdgcn_mfma_f32_16x16x32_bf16(af, wn, anh, 0, 0, 0);
        }

        // ---- E. sentinel-clear slot (t+2)%3 EARLY (widens clear->publish gap).
        //     Safe: our validation of h(t) proves every block published h(t),
        //     hence every block is past reading h(t-1) (the slot's content). ----
        if (t <= TT - 3 && (lcol & 1) == 0) {
            unsigned* cl = (unsigned*)(hbase + (size_t)((t + 2) % 3) * HSLOT_Q);
            #pragma unroll
            for (int j = 0; j < 4; ++j)
                st_d(cl + (((size_t)(brow + kgrp * 4 + j) * NH + hc0 + lcol) >> 1), SENTD);
        }

        // ---- F. x(t+1) prefetch (plain tracked loads) ----
        f32x4 xra[16], xrb[16];
        if (t + 1 < TT) {
            const float* xn = x + ((size_t)(brow + lcol) * TT + (t + 1)) * ND + kgrp * 8;
            #pragma unroll
            for (int it = 0; it < 16; ++it) {
                xra[it] = *(const f32x4*)(xn + it * 32);
                xrb[it] = *(const f32x4*)(xn + it * 32 + 4);
            }
        }

        // ---- G. gate math directly on accumulators ----
        float hn[4];
        #pragma unroll
        for (int j = 0; j < 4; ++j) {
            float r = sigmoid_f(ar[j] + b_r);
            float z = sigmoid_f(az[j] + b_z);
            float n = tanh_f(anx[j] + b_nx + r * (anh[j] + b_nh));
            hn[j] = (1.0f - z) * n + z * hp[j];
            hp[j] = hn[j];
        }

        // ---- H. convert x(t+1) -> bf16 (compiler-inserted exact waits) ----
        if (t + 1 < TT) {
            #pragma unroll
            for (int it = 0; it < 16; ++it) {
                bf16x8 f;
                f[0] = (__bf16)xra[it][0]; f[1] = (__bf16)xra[it][1];
                f[2] = (__bf16)xra[it][2]; f[3] = (__bf16)xra[it][3];
                f[4] = (__bf16)xrb[it][0]; f[5] = (__bf16)xrb[it][1];
                f[6] = (__bf16)xrb[it][2]; f[7] = (__bf16)xrb[it][3];
                xf[it] = f;
            }
        }

        // ---- I. publish h(t+1) (dword-atomic, store-and-forget) + out ----
        #pragma unroll
        for (int j = 0; j < 4; ++j) {
            unsigned hb16 = (unsigned)__builtin_bit_cast(unsigned short, (__bf16)hn[j]);
            unsigned nb16 = (unsigned)__shfl_xor((int)hb16, 1);
            if (t < TT - 1 && (lcol & 1) == 0) {
                unsigned* ps = (unsigned*)(hbase + (size_t)((t + 1) % 3) * HSLOT_Q);
                st_d(ps + (((size_t)(brow + kgrp * 4 + j) * NH + hc0 + lcol) >> 1),
                     hb16 | (nb16 << 16));
            }
            out[((size_t)(brow + kgrp * 4 + j) * TT + t) * NH + hc0 + lcol] = hn[j];
            if (t == TT - 1)
                out[(size_t)NB * TT * NH + (size_t)(brow + kgrp * 4 + j) * NH + hc0 + lcol]
                    = hn[j];
        }
    }
}

extern "C" void kernel_launch(void* const* d_in, const int* in_sizes, int n_in,
                              void* d_out, int out_size, void* d_ws, size_t ws_size,
                              hipStream_t stream) {
    (void)in_sizes; (void)n_in; (void)out_size;
    const float* x    = (const float*)d_in[0];
    const float* W_ih = (const float*)d_in[1];
    const float* W_hh = (const float*)d_in[2];
    const float* b_ih = (const float*)d_in[3];
    const float* b_hh = (const float*)d_in[4];
    float* out = (float*)d_out;

    // ws: 3 rotating h slots (bf16), 3 * 128 KB
    u64* hbase = (u64*)d_ws;
    if (ws_size < 3 * HSLOT_Q * sizeof(u64)) return;
    hipMemsetAsync(hbase, 0x00, HSLOT_Q * sizeof(u64), stream);          // slot0 = h(0)=0
    hipMemsetAsync(hbase + HSLOT_Q, 0xFF, 2 * HSLOT_Q * sizeof(u64), stream);  // 1,2 = SENT

    const size_t smem_bytes = 147456;
    (void)hipFuncSetAttribute((const void*)gru_kernel,
                              hipFuncAttributeMaxDynamicSharedMemorySize, (int)smem_bytes);
    gru_kernel<<<GRID, NTH, smem_bytes, stream>>>(x, W_ih, W_hh, b_ih, b_hh, out, hbase);
}